// Round 2
// baseline (1953.052 us; speedup 1.0000x reference)
//
#include <hip/hip_runtime.h>

#define TSTEPS 2048
#define NBATCH 512
#define H1 64
#define H2 16

// 2^x hardware exp; exp(x) = exp2(x*log2e)
__device__ __forceinline__ float fsig(float x) {
    return __builtin_amdgcn_rcpf(1.0f + __builtin_amdgcn_exp2f(-1.4426950408889634f * x));
}
__device__ __forceinline__ float ftanh(float x) {
    // tanh(x) = 1 - 2/(exp2(2x*log2e)+1); saturates correctly at +-inf
    return 1.0f - 2.0f * __builtin_amdgcn_rcpf(1.0f + __builtin_amdgcn_exp2f(2.8853900817779268f * x));
}

__global__ __launch_bounds__(256, 2) void lstm2_fused(
    const float* __restrict__ x,      // [512, 2048, 1]
    const float* __restrict__ w_ih1,  // [256, 1]
    const float* __restrict__ w_hh1,  // [256, 64]
    const float* __restrict__ b_ih1,  // [256]
    const float* __restrict__ b_hh1,  // [256]
    const float* __restrict__ w_ih2,  // [64, 64]
    const float* __restrict__ w_hh2,  // [64, 16]
    const float* __restrict__ b_ih2,  // [64]
    const float* __restrict__ b_hh2,  // [64]
    float* __restrict__ out)          // [512, 2048, 16]
{
    const int b   = blockIdx.x;
    const int tid = threadIdx.x;

    __shared__ float x_lds[TSTEPS];
    __shared__ float gbuf[256];      // activated layer-1 gates
    __shared__ float h1_lds[H1];
    __shared__ float g2buf[4 * H2];  // activated layer-2 gates
    __shared__ float h2_lds[H2];

    // ---- stage x[b, :] into LDS (coalesced float4) ----
    {
        const float4* xs = reinterpret_cast<const float4*>(x + (size_t)b * TSTEPS);
        float4* xd = reinterpret_cast<float4*>(x_lds);
        #pragma unroll
        for (int i = 0; i < TSTEPS / 4 / 256; ++i)
            xd[tid + 256 * i] = xs[tid + 256 * i];
    }

    // ---- weights stationary in registers ----
    // layer 1: thread owns gate row `tid` of W_hh1 (64 floats)
    float wr[H1];
    {
        const float4* w4 = reinterpret_cast<const float4*>(w_hh1 + tid * H1);
        #pragma unroll
        for (int kk = 0; kk < H1 / 4; ++kk) {
            float4 v = w4[kk];
            wr[4*kk+0] = v.x; wr[4*kk+1] = v.y; wr[4*kk+2] = v.z; wr[4*kk+3] = v.w;
        }
    }
    const float wih1_g = w_ih1[tid];
    const float bsum1  = b_ih1[tid] + b_hh1[tid];
    const bool  tanh1  = ((tid >> 6) == 2);   // wave-uniform: rows 128..191 are g-gate

    // layer 2: gate row g2 = tid>>2, k-quarter q = tid&3
    const int g2 = tid >> 2;
    const int q  = tid & 3;
    float wi2[16];
    {
        const float4* w4 = reinterpret_cast<const float4*>(w_ih2 + g2 * H1 + q * 16);
        #pragma unroll
        for (int kk = 0; kk < 4; ++kk) {
            float4 v = w4[kk];
            wi2[4*kk+0] = v.x; wi2[4*kk+1] = v.y; wi2[4*kk+2] = v.z; wi2[4*kk+3] = v.w;
        }
    }
    float wh2[4];
    {
        float4 v = *reinterpret_cast<const float4*>(w_hh2 + g2 * H2 + q * 4);
        wh2[0] = v.x; wh2[1] = v.y; wh2[2] = v.z; wh2[3] = v.w;
    }
    const float bsum2 = b_ih2[g2] + b_hh2[g2];
    const bool  tanh2 = ((g2 >> 4) == 2);     // wave-uniform: wave2 holds g-gate rows

    float c1 = 0.0f;   // wave0 lane j owns c1[j]
    float c2 = 0.0f;   // wave1 lanes 0..15 own c2[m]
    if (tid < H1) h1_lds[tid] = 0.0f;
    if (tid < H2) h2_lds[tid] = 0.0f;
    __syncthreads();

    float* outb = out + (size_t)b * TSTEPS * H2;

    // Layer 2 runs one timestep behind layer 1 -> 2 barriers per step.
    for (int t = 0; t <= TSTEPS; ++t) {
        // ---------- Phase A (all 256 threads) ----------
        float s1 = 0.0f;
        if (t < TSTEPS) s1 = x_lds[t] * wih1_g + bsum1;

        // layer-2 recurrent partial (timestep t-1): h2_lds holds h2(t-2)
        float p2;
        {
            float4 h2c = reinterpret_cast<const float4*>(h2_lds)[q];
            p2 = wh2[0]*h2c.x + wh2[1]*h2c.y + wh2[2]*h2c.z + wh2[3]*h2c.w;
        }

        const float4* h14 = reinterpret_cast<const float4*>(h1_lds);
        if (t < TSTEPS) {
            #pragma unroll
            for (int kk = 0; kk < 16; ++kk) {   // broadcast reads, 64 FMA
                float4 h = h14[kk];
                s1 += wr[4*kk+0]*h.x;
                s1 += wr[4*kk+1]*h.y;
                s1 += wr[4*kk+2]*h.z;
                s1 += wr[4*kk+3]*h.w;
            }
        }
        // layer-2 input partial: this thread's k-quarter of h1(t-1)
        #pragma unroll
        for (int c = 0; c < 4; ++c) {
            float4 h = h14[q * 4 + c];
            p2 += wi2[4*c+0]*h.x + wi2[4*c+1]*h.y + wi2[4*c+2]*h.z + wi2[4*c+3]*h.w;
        }

        if (t < TSTEPS) {
            gbuf[tid] = tanh1 ? ftanh(s1) : fsig(s1);   // activate own gate row
        }

        // reduce layer-2 partial across the 4 k-quarters (same wave)
        p2 += __shfl_xor(p2, 1);
        p2 += __shfl_xor(p2, 2);
        if (t >= 1 && q == 0) {
            float tot = p2 + bsum2;
            g2buf[g2] = tanh2 ? ftanh(tot) : fsig(tot);
        }
        __syncthreads();

        // ---------- Phase B (state update) ----------
        if (t < TSTEPS && tid < H1) {           // wave 0: layer-1 cell update
            float gi = gbuf[tid];
            float gf = gbuf[tid + 64];
            float gg = gbuf[tid + 128];
            float go = gbuf[tid + 192];
            c1 = gf * c1 + gi * gg;
            h1_lds[tid] = go * ftanh(c1);
        }
        if (t >= 1 && tid >= 64 && tid < 64 + H2) {  // wave 1: layer-2 cell update
            const int m = tid - 64;
            float gi = g2buf[m];
            float gf = g2buf[m + 16];
            float gg = g2buf[m + 32];
            float go = g2buf[m + 48];
            c2 = gf * c2 + gi * gg;
            float h = go * ftanh(c2);
            h2_lds[m] = h;
            outb[(size_t)(t - 1) * H2 + m] = h;
        }
        __syncthreads();
    }
}

extern "C" void kernel_launch(void* const* d_in, const int* in_sizes, int n_in,
                              void* d_out, int out_size, void* d_ws, size_t ws_size,
                              hipStream_t stream) {
    const float* x     = (const float*)d_in[0];
    const float* w_ih1 = (const float*)d_in[1];
    const float* w_hh1 = (const float*)d_in[2];
    const float* b_ih1 = (const float*)d_in[3];
    const float* b_hh1 = (const float*)d_in[4];
    const float* w_ih2 = (const float*)d_in[5];
    const float* w_hh2 = (const float*)d_in[6];
    const float* b_ih2 = (const float*)d_in[7];
    const float* b_hh2 = (const float*)d_in[8];
    float* out = (float*)d_out;

    lstm2_fused<<<NBATCH, 256, 0, stream>>>(x, w_ih1, w_hh1, b_ih1, b_hh1,
                                            w_ih2, w_hh2, b_ih2, b_hh2, out);
}

// Round 3
// 1876.728 us; speedup vs baseline: 1.0407x; 1.0407x over previous
//
#include <hip/hip_runtime.h>

#define TSTEPS 2048
#define NBATCH 512
#define H1 64
#define H2 16

__device__ __forceinline__ float fsig(float x) {
    return __builtin_amdgcn_rcpf(1.0f + __builtin_amdgcn_exp2f(-1.4426950408889634f * x));
}
__device__ __forceinline__ float ftanh(float x) {
    // tanh(x) = 1 - 2/(exp2(2x*log2e)+1); saturates correctly at +-inf
    return 1.0f - 2.0f * __builtin_amdgcn_rcpf(1.0f + __builtin_amdgcn_exp2f(2.8853900817779268f * x));
}

// DPP cross-lane add (VALU pipe, not LDS): v += v[lane mapped by CTRL]
#define DPP_QUAD_XOR1   0xB1   // quad_perm [1,0,3,2]
#define DPP_QUAD_XOR2   0x4E   // quad_perm [2,3,0,1]
#define DPP_HALF_MIRROR 0x141  // mirror within 8-lane half-row (xor-ish 4-swap)
template<int CTRL>
__device__ __forceinline__ float dpp_add(float v) {
    int m = __builtin_amdgcn_mov_dpp(__float_as_int(v), CTRL, 0xF, 0xF, true);
    return v + __int_as_float(m);
}

__global__ void __launch_bounds__(256)
__attribute__((amdgpu_waves_per_eu(2, 2)))   // grid gives exactly 2 waves/SIMD; free the allocator to 256 VGPRs
lstm2_fused(const float* __restrict__ x,      // [512, 2048, 1]
            const float* __restrict__ w_ih1,  // [256, 1]
            const float* __restrict__ w_hh1,  // [256, 64]
            const float* __restrict__ b_ih1,  // [256]
            const float* __restrict__ b_hh1,  // [256]
            const float* __restrict__ w_ih2,  // [64, 64]
            const float* __restrict__ w_hh2,  // [64, 16]
            const float* __restrict__ b_ih2,  // [64]
            const float* __restrict__ b_hh2,  // [64]
            float* __restrict__ out)          // [512, 2048, 16]
{
    const int b   = blockIdx.x;
    const int tid = threadIdx.x;

    __shared__ float x_lds[TSTEPS];
    __shared__ float h1buf[2][H1];   // double-buffered h1 (parity by t)
    __shared__ float h2buf[2][H2];   // double-buffered h2

    // ---- stage x[b,:] (8 KB), zero state buffers ----
    {
        const float4* xs = reinterpret_cast<const float4*>(x + (size_t)b * TSTEPS);
        float4* xd = reinterpret_cast<float4*>(x_lds);
        xd[tid]       = xs[tid];
        xd[tid + 256] = xs[tid + 256];
    }
    if (tid < 2 * H1) ((float*)h1buf)[tid] = 0.0f;
    if (tid < 2 * H2) ((float*)h2buf)[tid] = 0.0f;

    // ---- Layer 1 mapping: channel j = tid>>2, k-quarter q = tid&3 ----
    // Thread owns ALL FOUR gate rows {j, 64+j, 128+j, 192+j}, k-slice [q*16, q*16+16)
    const int j = tid >> 2;
    const int q = tid & 3;
    float w1[4][16];
    float wx1[4], bs1[4];
    #pragma unroll
    for (int g = 0; g < 4; ++g) {
        const int r = g * H1 + j;
        const float4* w4 = reinterpret_cast<const float4*>(w_hh1 + r * H1 + q * 16);
        #pragma unroll
        for (int kk = 0; kk < 4; ++kk) {
            float4 v = w4[kk];
            w1[g][4*kk+0] = v.x; w1[g][4*kk+1] = v.y;
            w1[g][4*kk+2] = v.z; w1[g][4*kk+3] = v.w;
        }
        wx1[g] = w_ih1[r];
        bs1[g] = b_ih1[r] + b_hh1[r];
    }
    // Pin weights into VGPRs: opaque defs kill the compiler's load-sinking
    // (round-2 evidence: VGPR_Count=64 + FETCH_SIZE 2.4 GB = weights re-read every step)
    #pragma unroll
    for (int g = 0; g < 4; ++g) {
        #pragma unroll
        for (int k = 0; k < 16; ++k) asm volatile("" : "+v"(w1[g][k]));
        asm volatile("" : "+v"(wx1[g]), "+v"(bs1[g]));
    }

    // ---- Layer 2 mapping (threads 0..127, waves 0-1): channel m = tid>>3, octant oc = tid&7 ----
    // Thread owns all 4 gate rows {m, 16+m, 32+m, 48+m}; w_ih2 k-slice of 8, w_hh2 k-slice of 2
    const int m  = tid >> 3;
    const int oc = tid & 7;
    float w2[4][8], wh2[4][2], bs2[4];
    if (tid < 128) {
        #pragma unroll
        for (int g = 0; g < 4; ++g) {
            const int r2 = g * H2 + m;
            const float4* w4 = reinterpret_cast<const float4*>(w_ih2 + r2 * H1 + oc * 8);
            float4 v0 = w4[0], v1 = w4[1];
            w2[g][0]=v0.x; w2[g][1]=v0.y; w2[g][2]=v0.z; w2[g][3]=v0.w;
            w2[g][4]=v1.x; w2[g][5]=v1.y; w2[g][6]=v1.z; w2[g][7]=v1.w;
            float2 vh = *reinterpret_cast<const float2*>(w_hh2 + r2 * H2 + oc * 2);
            wh2[g][0] = vh.x; wh2[g][1] = vh.y;
            bs2[g] = b_ih2[r2] + b_hh2[r2];
        }
        #pragma unroll
        for (int g = 0; g < 4; ++g) {
            #pragma unroll
            for (int k = 0; k < 8; ++k) asm volatile("" : "+v"(w2[g][k]));
            asm volatile("" : "+v"(wh2[g][0]), "+v"(wh2[g][1]), "+v"(bs2[g]));
        }
    }

    float c1 = 0.0f;   // replicated across the 4 q-lanes of channel j
    float c2 = 0.0f;   // replicated across the 8 oc-lanes of channel m
    __syncthreads();

    float* outb = out + (size_t)b * TSTEPS * H2;

    // Layer 2 runs one step behind layer 1; ONE barrier per step.
    for (int t = 0; t <= TSTEPS; ++t) {
        const int ri = t & 1;                 // read slot: h1buf[ri]=h1(t-1), h2buf[ri]=h2(t-2)
        const float* h1o = h1buf[ri];

        // ===== Layer 2: computes timestep t-1 (waves 0-1 only; wave-uniform branch) =====
        if (tid < 128) {
            const float4* h4 = reinterpret_cast<const float4*>(h1o + oc * 8);
            float4 a0 = h4[0], a1 = h4[1];
            float h2a = h2buf[ri][oc * 2], h2b = h2buf[ri][oc * 2 + 1];
            float p[4];
            #pragma unroll
            for (int g = 0; g < 4; ++g) {
                float s = w2[g][0]*a0.x + w2[g][1]*a0.y + w2[g][2]*a0.z + w2[g][3]*a0.w;
                s      += w2[g][4]*a1.x + w2[g][5]*a1.y + w2[g][6]*a1.z + w2[g][7]*a1.w;
                s      += wh2[g][0]*h2a + wh2[g][1]*h2b;
                // all-reduce across the 8 oc-lanes on the VALU pipe
                s = dpp_add<DPP_QUAD_XOR1>(s);
                s = dpp_add<DPP_QUAD_XOR2>(s);
                s = dpp_add<DPP_HALF_MIRROR>(s);
                p[g] = s + bs2[g];
            }
            if (t >= 1) {
                float gi = fsig(p[0]), gf = fsig(p[1]), gg = ftanh(p[2]), go = fsig(p[3]);
                c2 = gf * c2 + gi * gg;
                float h2n = go * ftanh(c2);
                if (oc == 0) {
                    h2buf[ri ^ 1][m] = h2n;
                    outb[(size_t)(t - 1) * H2 + m] = h2n;
                }
            }
        }

        // ===== Layer 1: timestep t =====
        if (t < TSTEPS) {
            const float4* h4 = reinterpret_cast<const float4*>(h1o + q * 16);
            float4 v0 = h4[0], v1 = h4[1], v2 = h4[2], v3 = h4[3];
            const float x_t = x_lds[t];
            float pre[4];
            #pragma unroll
            for (int g = 0; g < 4; ++g) {
                float s = w1[g][0] *v0.x + w1[g][1] *v0.y + w1[g][2] *v0.z + w1[g][3] *v0.w;
                s      += w1[g][4] *v1.x + w1[g][5] *v1.y + w1[g][6] *v1.z + w1[g][7] *v1.w;
                s      += w1[g][8] *v2.x + w1[g][9] *v2.y + w1[g][10]*v2.z + w1[g][11]*v2.w;
                s      += w1[g][12]*v3.x + w1[g][13]*v3.y + w1[g][14]*v3.z + w1[g][15]*v3.w;
                // all-reduce across the 4 q-lanes (VALU DPP)
                s = dpp_add<DPP_QUAD_XOR1>(s);
                s = dpp_add<DPP_QUAD_XOR2>(s);
                pre[g] = s + (x_t * wx1[g] + bs1[g]);
            }
            // fixed gate roles -> no divergence, no selects
            float gi = fsig(pre[0]), gf = fsig(pre[1]), gg = ftanh(pre[2]), go = fsig(pre[3]);
            c1 = gf * c1 + gi * gg;
            float h1n = go * ftanh(c1);
            if (q == 0) h1buf[ri ^ 1][j] = h1n;
        }

        __syncthreads();   // h1(t)/h2(t-1) visible for step t+1
    }
}

extern "C" void kernel_launch(void* const* d_in, const int* in_sizes, int n_in,
                              void* d_out, int out_size, void* d_ws, size_t ws_size,
                              hipStream_t stream) {
    const float* x     = (const float*)d_in[0];
    const float* w_ih1 = (const float*)d_in[1];
    const float* w_hh1 = (const float*)d_in[2];
    const float* b_ih1 = (const float*)d_in[3];
    const float* b_hh1 = (const float*)d_in[4];
    const float* w_ih2 = (const float*)d_in[5];
    const float* w_hh2 = (const float*)d_in[6];
    const float* b_ih2 = (const float*)d_in[7];
    const float* b_hh2 = (const float*)d_in[8];
    float* out = (float*)d_out;

    lstm2_fused<<<NBATCH, 256, 0, stream>>>(x, w_ih1, w_hh1, b_ih1, b_hh1,
                                            w_ih2, w_hh2, b_ih2, b_hh2, out);
}